// Round 3
// baseline (184.535 us; speedup 1.0000x reference)
//
#include <hip/hip_runtime.h>
#include <stdint.h>

#define BN 4096
#define DD 128
#define EPSF 1e-6f
#define MARGINF 1.0f

typedef unsigned long long ull;
typedef unsigned short ushort;
typedef short short8 __attribute__((ext_vector_type(8)));
typedef float f32x4 __attribute__((ext_vector_type(4)));

__device__ __forceinline__ unsigned int ord_f32(float f) {
    unsigned int u = __float_as_uint(f);
    return (u & 0x80000000u) ? ~u : (u | 0x80000000u);
}
__device__ __forceinline__ ushort bf16_rne(float x) {
    unsigned int u = __float_as_uint(x);
    return (ushort)((u + 0x7FFFu + ((u >> 16) & 1u)) >> 16);
}

// --- prep: bf16 convert of e (row order AND permuted-column order), per-column
//     tables (rjp, jn), key init. eperm[c] = bf16(e[inv[c]]) kills the per-lane
//     random-row gather in k_select (64 lines/instr -> 16 fully-used lines).
__global__ void k_prep(const float* __restrict__ e, const int* __restrict__ tidx,
                       float* __restrict__ rjp, unsigned int* __restrict__ jn,
                       ull* __restrict__ pk, ull* __restrict__ nk,
                       unsigned int* __restrict__ ehi, unsigned int* __restrict__ eperm) {
    int w = threadIdx.x >> 6, lane = threadIdx.x & 63;
    int row = blockIdx.x * 4 + w;
    int c = tidx[row];                       // wave-uniform broadcast load
    float2 v = ((const float2*)(e + (size_t)row * DD))[lane];
    ushort hx = bf16_rne(v.x), hy = bf16_rne(v.y);
    unsigned int packed = (unsigned int)hx | ((unsigned int)hy << 16);
    ehi[row * 64 + lane] = packed;
    eperm[(size_t)c * 64 + lane] = packed;   // scattered 256 B rows, 1 MB total
    float ss = v.x + v.y;
    float qq = v.x * v.x + v.y * v.y;
    #pragma unroll
    for (int off = 32; off > 0; off >>= 1) {
        ss += __shfl_down(ss, off);
        qq += __shfl_down(qq, off);
    }
    if (lane == 0) {
        rjp[c] = qq - 2.0f * EPSF * ss;      // column-indexed row-stat (same arithmetic)
        jn[c] = 0xFFFFFFFFu - (unsigned int)row;
        pk[row] = 0ULL; nk[row] = 0ULL;      // both max-merged (neg uses inverted keys)
    }
}

// --- fused MFMA + selection; block = 16 rows x 1024 cols ---
// B rows now come CONTIGUOUSLY from eperm (no per-lane gather): every vector
// load is fully-consumed 64 B lines. Masks are nontemporal (single-use stream)
// so they don't evict ehi/eperm from L2. No barriers in the main loop.
__global__ __launch_bounds__(256, 4)
void k_select(const ushort* __restrict__ ehi, const ushort* __restrict__ eperm,
              const int* __restrict__ pos, const int* __restrict__ neg,
              const float* __restrict__ rjp, const unsigned int* __restrict__ jn,
              ull* __restrict__ pkey, ull* __restrict__ nkey) {
    __shared__ float rjL[1024];
    __shared__ unsigned int jnL[1024];
    __shared__ ull scrp[16 * 4], scrn[16 * 4];

    const int tid = threadIdx.x;
    const int lane = tid & 63, w = tid >> 6;
    const int lrow = lane & 15, quad = lane >> 4;
    const int r0 = blockIdx.x * 16;
    const int c0 = blockIdx.y * 1024;

    // stage per-column tables once (columns c0..c0+1023)
    #pragma unroll
    for (int k = 0; k < 4; k++) {
        int idx = k * 256 + tid;
        rjL[idx] = rjp[c0 + idx];
        jnL[idx] = jn[c0 + idx];
    }

    // A fragments: 16 rows, loaded ONCE, reused for all 16 column tiles
    short8 a[4];
    #pragma unroll
    for (int ks = 0; ks < 4; ks++)
        a[ks] = *(const short8*)(ehi + (size_t)(r0 + lrow) * DD + ks * 32 + quad * 8);

    __syncthreads();

    ull kp[4] = {0ULL, 0ULL, 0ULL, 0ULL};
    ull kn[4] = {0ULL, 0ULL, 0ULL, 0ULL};

    // double-buffered prefetch state (one 64-col tile ahead)
    int pm[2][4], nm[2][4];
    short8 bf[2][4];
    float rjc[2]; unsigned int jni[2];

#define LOADTILE(BUF, JT) do {                                                 \
        const int lcol = (JT) * 64 + w * 16 + lrow;                            \
        rjc[BUF] = rjL[lcol];                                                  \
        jni[BUF] = jnL[lcol];                                                  \
        const int* pp = pos + (size_t)(r0 + quad * 4) * BN + (size_t)(c0 + lcol); \
        const int* np = neg + (size_t)(r0 + quad * 4) * BN + (size_t)(c0 + lcol); \
        _Pragma("unroll")                                                      \
        for (int t = 0; t < 4; t++) {                                          \
            pm[BUF][t] = __builtin_nontemporal_load(pp + (size_t)t * BN);      \
            nm[BUF][t] = __builtin_nontemporal_load(np + (size_t)t * BN);      \
        }                                                                      \
        const ushort* bp = eperm + (size_t)(c0 + lcol) * DD + quad * 8;        \
        _Pragma("unroll")                                                      \
        for (int ks = 0; ks < 4; ks++)                                         \
            bf[BUF][ks] = *(const short8*)(bp + ks * 32);                      \
    } while (0)

    LOADTILE(0, 0);

    #pragma unroll
    for (int jt = 0; jt < 16; jt++) {
        const int cur = jt & 1, nxt = cur ^ 1;
        if (jt < 15) {
            if (nxt == 0) LOADTILE(0, jt + 1); else LOADTILE(1, jt + 1);
        }
        f32x4 acc = (f32x4){0.f, 0.f, 0.f, 0.f};
        #pragma unroll
        for (int ks = 0; ks < 4; ks++)
            acc = __builtin_amdgcn_mfma_f32_16x16x32_bf16(a[ks], bf[cur][ks], acc, 0, 0, 0);
        // selection on m = rj - 2*dot (row-constant terms dropped)
        #pragma unroll
        for (int t = 0; t < 4; t++) {
            float m = rjc[cur] - 2.0f * acc[t];
            unsigned int om = ord_f32(m);
            ull keyp = ((ull)om << 32) | (ull)jni[cur];
            ull keyn = ((ull)(om ^ 0xFFFFFFFFu) << 32) | (ull)jni[cur];
            if (pm[cur][t] != 0 && keyp > kp[t]) kp[t] = keyp;   // max-m, ties -> smaller j
            if (nm[cur][t] != 0 && keyn > kn[t]) kn[t] = keyn;   // min-m, ties -> smaller j
        }
    }
#undef LOADTILE

    // fold across the 16 lanes of each quad (all hold same rows, different cols)
    #pragma unroll
    for (int t = 0; t < 4; t++) {
        #pragma unroll
        for (int off = 8; off > 0; off >>= 1) {
            ull o = __shfl_xor(kp[t], off); if (o > kp[t]) kp[t] = o;
            o = __shfl_xor(kn[t], off);     if (o > kn[t]) kn[t] = o;
        }
        if (lrow == 0) {
            scrp[(quad * 4 + t) * 4 + w] = kp[t];
            scrn[(quad * 4 + t) * 4 + w] = kn[t];
        }
    }
    __syncthreads();
    if (tid < 16) {
        ull xp = 0ULL, xn = 0ULL;
        #pragma unroll
        for (int k = 0; k < 4; k++) {
            ull v = scrp[tid * 4 + k]; if (v > xp) xp = v;
            v = scrn[tid * 4 + k];     if (v > xn) xn = v;
        }
        if (xp) atomicMax(&pkey[r0 + tid], xp);
        if (xn) atomicMax(&nkey[r0 + tid], xn);
    }
}

// --- per-row triplet loss: wave per row (coalesced), block partials ---
__global__ void k_loss(const float* __restrict__ e,
                       const ull* __restrict__ pkey, const ull* __restrict__ nkey,
                       float* __restrict__ partials) {
    int w = threadIdx.x >> 6, lane = threadIdx.x & 63;
    int row = blockIdx.x * 4 + w;
    ull pk = pkey[row], nk = nkey[row];
    float loss = 0.0f, wt = 0.0f;
    if (pk != 0ULL && nk != 0ULL) {
        int pi = (int)(0xFFFFFFFFu - (unsigned)(pk & 0xFFFFFFFFu));
        int ni = (int)(0xFFFFFFFFu - (unsigned)(nk & 0xFFFFFFFFu));
        float2 av = ((const float2*)(e + (size_t)row * DD))[lane];
        float2 pv = ((const float2*)(e + (size_t)pi * DD))[lane];
        float2 nv = ((const float2*)(e + (size_t)ni * DD))[lane];
        float dx, dy;
        dx = av.x - pv.x + EPSF; dy = av.y - pv.y + EPSF;
        float ap2 = dx * dx + dy * dy;
        dx = av.x - nv.x + EPSF; dy = av.y - nv.y + EPSF;
        float an2 = dx * dx + dy * dy;
        dx = pv.x - nv.x + EPSF; dy = pv.y - nv.y + EPSF;
        float pn2 = dx * dx + dy * dy;
        #pragma unroll
        for (int off = 32; off > 0; off >>= 1) {
            ap2 += __shfl_down(ap2, off);
            an2 += __shfl_down(an2, off);
            pn2 += __shfl_down(pn2, off);
        }
        if (lane == 0) {
            float ap = sqrtf(ap2), an = sqrtf(an2), pn = sqrtf(pn2);
            loss = fmaxf(ap - fminf(an, pn) + MARGINF, 0.0f);
            wt = 1.0f;
        }
    }
    __shared__ float sl[4], sw[4];
    if (lane == 0) { sl[w] = loss; sw[w] = wt; }
    __syncthreads();
    if (threadIdx.x == 0) {
        partials[blockIdx.x * 2 + 0] = sl[0] + sl[1] + sl[2] + sl[3];
        partials[blockIdx.x * 2 + 1] = sw[0] + sw[1] + sw[2] + sw[3];
    }
}

// --- finalize ---
__global__ void k_final(const float* __restrict__ partials, float* __restrict__ out) {
    int tid = threadIdx.x;
    float L = 0.0f, W = 0.0f;
    for (int i = 0; i < 4; i++) {
        int idx = tid + i * 256;
        L += partials[idx * 2];
        W += partials[idx * 2 + 1];
    }
    #pragma unroll
    for (int off = 32; off > 0; off >>= 1) {
        L += __shfl_down(L, off);
        W += __shfl_down(W, off);
    }
    __shared__ float sl[4], sw[4];
    int w = tid >> 6, lane = tid & 63;
    if (lane == 0) { sl[w] = L; sw[w] = W; }
    __syncthreads();
    if (tid == 0) {
        float Lt = sl[0] + sl[1] + sl[2] + sl[3];
        float Wt = sw[0] + sw[1] + sw[2] + sw[3];
        out[0] = Lt / fmaxf(Wt, 1.0f);
    }
}

extern "C" void kernel_launch(void* const* d_in, const int* in_sizes, int n_in,
                              void* d_out, int out_size, void* d_ws, size_t ws_size,
                              hipStream_t stream) {
    const float* e    = (const float*)d_in[0];
    const int*   tidx = (const int*)d_in[1];
    const int*   pos  = (const int*)d_in[2];
    const int*   neg  = (const int*)d_in[3];
    float* out = (float*)d_out;

    ull* pkey  = (ull*)d_ws;                          // 4096 ull
    ull* nkey  = pkey + BN;                           // 4096 ull
    float* rjp = (float*)(nkey + BN);                 // 4096 f32
    unsigned int* jn = (unsigned int*)(rjp + BN);     // 4096 u32
    float* partials  = (float*)(jn + BN);             // 2048 f32
    unsigned int* ehi   = (unsigned int*)(partials + 2048);   // 4096*64 u32
    unsigned int* eperm = ehi + (size_t)BN * 64;              // 4096*64 u32

    k_prep<<<BN / 4, 256, 0, stream>>>(e, tidx, rjp, jn, pkey, nkey, ehi, eperm);
    dim3 grid(BN / 16, 4);
    k_select<<<grid, 256, 0, stream>>>((const ushort*)ehi, (const ushort*)eperm,
                                       pos, neg, rjp, jn, pkey, nkey);
    k_loss<<<BN / 4, 256, 0, stream>>>(e, pkey, nkey, partials);
    k_final<<<1, 256, 0, stream>>>(partials, out);
}